// Round 1
// baseline (244.692 us; speedup 1.0000x reference)
//
#include <hip/hip_runtime.h>
#include <hip/hip_bf16.h>

// Problem constants
#define LNUM 8
#define ENUM 8
#define DDIM 256
#define BSZ  16384
#define H1N  64
#define H2N  32

#define BT   32     // rows per block (halved: grid 512 -> 2 blocks/CU)
#define NTHR 512    // 8 waves

// LDS pitches (u16 elements); odd 16B-granule strides -> conflict-light
#define PX   264    // x tile (D + 8)
#define PH1  72     // h1T tile (H1 + 8)   [row][feat]
#define PH2  40     // h2T tile (H2 + 8)   [row][feat]
#define PSW  9      // softmax weights pitch (floats)

// ws element offsets (u16 elems) for fragment-ordered weights
#define WS1_OFF 0           // 64 steps * 16384 elems
#define WS2_OFF 1048576     // 64 steps * 2048
#define WS3_OFF 1179648     // 64 steps * 8192

typedef float f32x4 __attribute__((ext_vector_type(4)));
typedef unsigned short u16x8 __attribute__((ext_vector_type(8)));
typedef unsigned short u16x4 __attribute__((ext_vector_type(4)));
typedef __bf16 bf16x8 __attribute__((ext_vector_type(8)));

#define Z4 ((f32x4){0.f, 0.f, 0.f, 0.f})

// Round-to-nearest-even f32 -> bf16 (truncation bias compounds over 24 GEMMs).
static __device__ __forceinline__ unsigned short f2bf(float f) {
    unsigned u = __builtin_bit_cast(unsigned, f);
    u += 0x7fffu + ((u >> 16) & 1u);
    return (unsigned short)(u >> 16);
}

// D[m][n] = sum_k A[m][k]*B[n][k] + C : A supplies m, B supplies n, frags are
// symmetric [idx16][K] -> swapping args transposes the output tile.
static __device__ __forceinline__ f32x4 mfma16(u16x8 a, u16x8 b, f32x4 c) {
    return __builtin_amdgcn_mfma_f32_16x16x32_bf16(
        __builtin_bit_cast(bf16x8, a), __builtin_bit_cast(bf16x8, b), c, 0, 0, 0);
}

// ---------------------------------------------------------------------------
// Kernel 1: fp32 weights -> bf16 B-fragment layout. Coalesced reads,
// scattered 16B fragment writes (L2 merges). Unchanged.
// Fragment: 64 lanes x 8 elems; slot (q*16+r) holds W[n0+r][k0+q*8 .. +7].
// ---------------------------------------------------------------------------
__global__ __launch_bounds__(256) void cvt_w_frag(
    const float* __restrict__ w1, const float* __restrict__ w2,
    const float* __restrict__ w3, unsigned short* __restrict__ ws)
{
    int gid = blockIdx.x * 256 + threadIdx.x;
    const float* src;
    unsigned short* dst;
    if (gid < 131072) {                          // W1: [s][n(64)][k(256)]
        int s = gid >> 11, rem = gid & 2047;
        int n = rem >> 5, kc = rem & 31;
        int nt = n >> 4, r = n & 15, kt = kc >> 2, q = kc & 3;
        src = w1 + (size_t)gid * 8;
        dst = ws + WS1_OFF + (size_t)s * 16384 + nt * 4096 + kt * 512 + (q * 16 + r) * 8;
    } else if (gid < 147456) {                   // W2: [s][n(32)][k(64)]
        int g = gid - 131072;
        int s = g >> 8, rem = g & 255;
        int n = rem >> 3, kc = rem & 7;
        int n2 = n >> 4, r = n & 15, kt = kc >> 2, q = kc & 3;
        src = w2 + (size_t)g * 8;
        dst = ws + WS2_OFF + (size_t)s * 2048 + n2 * 1024 + kt * 512 + (q * 16 + r) * 8;
    } else {                                     // W3: [s][n(256)][k(32)]
        int g = gid - 147456;
        int s = g >> 10, rem = g & 1023;
        int n = rem >> 2, q = rem & 3;
        int nt = n >> 4, r = n & 15;
        src = w3 + (size_t)g * 8;
        dst = ws + WS3_OFF + (size_t)s * 8192 + nt * 512 + (q * 16 + r) * 8;
    }
    float4 a = *(const float4*)src;
    float4 b = *(const float4*)(src + 4);
    u16x8 p;
    p[0] = f2bf(a.x); p[1] = f2bf(a.y); p[2] = f2bf(a.z); p[3] = f2bf(a.w);
    p[4] = f2bf(b.x); p[5] = f2bf(b.y); p[6] = f2bf(b.z); p[7] = f2bf(b.w);
    *(u16x8*)dst = p;
}

// ---------------------------------------------------------------------------
// Kernel 2: fused 8-layer x 8-expert MoE MLP, 2-expert supersteps.
// BT=32 / grid=512: 2 independent blocks per CU (16 waves/CU) so one block's
// compute overlaps the other block's barrier/load stalls.
// Per wave: wm = row-tile (16 rows), wn = feat/col group.
// G2 splits waves by expert (ex=wm), quadrant (r2,f2)=(wn&1,wn>>1).
// ---------------------------------------------------------------------------
__global__ __launch_bounds__(NTHR, 4) void moe_fused(
    const float* __restrict__ src, const unsigned short* __restrict__ Wf,
    const float* __restrict__ b1, const float* __restrict__ b2,
    const float* __restrict__ b3, const float* __restrict__ masks,
    float* __restrict__ out)
{
    __shared__ __align__(16) unsigned short Xlds[BT * PX];        // 16896 B
    __shared__ __align__(16) unsigned short H1T[2][BT * PH1];     //  9216 B [row][feat]
    __shared__ __align__(16) unsigned short H2T[2][BT * PH2];     //  5120 B [row][feat]
    __shared__ float SWlds[BT * PSW];                             //  1152 B
    // total 32384 B -> 2 blocks/CU fit easily

    const int tid  = threadIdx.x;
    const int lane = tid & 63;
    const int w    = tid >> 6;
    const int wm   = w >> 2;        // {0,1}: row-tile (G1/G3), expert (G2)
    const int wn   = w & 3;         // {0..3}: feat group (G1), col group (G3)
    const int r2   = wn & 1;        // G2 row group
    const int f2   = wn >> 1;       // G2 feat group
    const int n15  = lane & 15;
    const int q    = lane >> 4;
    const int b0   = blockIdx.x * BT;

    const unsigned short* w1base = Wf + WS1_OFF + wn * 4096 + lane * 8;  // feat grp wn
    const unsigned short* w2base = Wf + WS2_OFF + f2 * 1024 + lane * 8;  // feat grp f2
    const unsigned short* w3base = Wf + WS3_OFF + wn * 2048 + lane * 8;  // out grp wn

    u16x8 xf[8];             // persistent x B-frags: rows wm*16, K=256
    f32x4 ACC[4];            // output accumulator (C-layout: row=q*4+rg, col=n15)

    auto stage_softmax = [&](int l) {
        if (tid < BT) {
            const float* mp = masks + ((size_t)l * BSZ + b0 + tid) * ENUM;
            float4 m0 = *(const float4*)mp;
            float4 m1 = *(const float4*)(mp + 4);
            float mv[8] = {m0.x, m0.y, m0.z, m0.w, m1.x, m1.y, m1.z, m1.w};
            float mx = mv[0];
            #pragma unroll
            for (int e = 1; e < 8; ++e) mx = fmaxf(mx, mv[e]);
            float s = 0.f;
            #pragma unroll
            for (int e = 0; e < 8; ++e) { mv[e] = expf(mv[e] - mx); s += mv[e]; }
            float inv = 1.f / s;
            #pragma unroll
            for (int e = 0; e < 8; ++e) SWlds[tid * PSW + e] = mv[e] * inv;
        }
    };

    // ACC = sum_e softmax_w[row][e] * b3[e][col]  (fp32 VALU, once per layer)
    auto acc_init = [&](int l) {
        const float* b3l = b3 + (size_t)l * ENUM * DDIM;
        #pragma unroll
        for (int nt = 0; nt < 4; ++nt) ACC[nt] = Z4;
        #pragma unroll 2
        for (int e2 = 0; e2 < ENUM; ++e2) {
            float swv[4];
            #pragma unroll
            for (int rg = 0; rg < 4; ++rg)
                swv[rg] = SWlds[(wm*16 + q*4 + rg) * PSW + e2];
            #pragma unroll
            for (int nt = 0; nt < 4; ++nt) {
                float bv = b3l[e2 * DDIM + wn*64 + nt*16 + n15];
                #pragma unroll
                for (int rg = 0; rg < 4; ++rg)
                    ACC[nt][rg] += swv[rg] * bv;
            }
        }
    };

    auto xf_read = [&]() {
        #pragma unroll
        for (int kt = 0; kt < 8; ++kt)
            xf[kt] = *(const u16x8*)&Xlds[(wm*16 + n15) * PX + q*8 + kt*32];
    };
    auto x_write = [&]() {
        #pragma unroll
        for (int nt = 0; nt < 4; ++nt)
            #pragma unroll
            for (int rg = 0; rg < 4; ++rg)
                Xlds[(wm*16 + q*4 + rg) * PX + wn*64 + nt*16 + n15] =
                    f2bf(ACC[nt][rg]);
    };

    // ================= prologue =================
    #pragma unroll
    for (int i = 0; i < 2; ++i) {                // stage layer-0 x (bf16)
        int o = (i * NTHR + tid) * 8;
        int r = o >> 8, c = o & 255;
        const float* p = src + (size_t)(b0 + r) * DDIM + c;
        float4 f0 = *(const float4*)(p);
        float4 f1 = *(const float4*)(p + 4);
        u16x8 pk;
        pk[0] = f2bf(f0.x); pk[1] = f2bf(f0.y); pk[2] = f2bf(f0.z); pk[3] = f2bf(f0.w);
        pk[4] = f2bf(f1.x); pk[5] = f2bf(f1.y); pk[6] = f2bf(f1.z); pk[7] = f2bf(f1.w);
        *(u16x8*)&Xlds[r * PX + c] = pk;
    }
    stage_softmax(0);
    __syncthreads();
    xf_read();
    acc_init(0);

    // ================= superstep loop: 2 experts per iteration =================
    #pragma unroll 1
    for (int ss = 0; ss < LNUM * ENUM / 2; ++ss) {
        const int s0 = 2 * ss, s1 = s0 + 1;
        const int l  = s0 >> 3, e0 = s0 & 7;

        // ---- superstep-top loads: W1 both experts, W2 (own expert), biases ----
        u16x8 wfA[8], wfB[8], w2f[2];
        {
            const unsigned short* pA = w1base + (size_t)s0 * 16384;
            const unsigned short* pB = w1base + (size_t)s1 * 16384;
            #pragma unroll
            for (int kt = 0; kt < 8; ++kt) {
                wfA[kt] = *(const u16x8*)(pA + kt * 512);
                wfB[kt] = *(const u16x8*)(pB + kt * 512);
            }
            const unsigned short* q2 = w2base + (size_t)(s0 + wm) * 2048;
            w2f[0] = *(const u16x8*)(q2);  w2f[1] = *(const u16x8*)(q2 + 512);
        }
        const float4 bb1A = *(const float4*)(b1 + s0 * 64 + wn * 16 + q * 4);
        const float4 bb1B = *(const float4*)(b1 + s1 * 64 + wn * 16 + q * 4);
        const float4 bb2  = *(const float4*)(b2 + (s0 + wm) * 32 + f2 * 16 + q * 4);

        // ---- G1 both experts (transposed): lane -> feats wn*16+q*4+rg,
        //      rows wm*16 .. +15; 2 independent chains, B-frag xf shared ----
        f32x4 a1A = Z4, a1B = Z4;
        #pragma unroll
        for (int kt = 0; kt < 8; ++kt) {
            a1A = mfma16(wfA[kt], xf[kt], a1A);
            a1B = mfma16(wfB[kt], xf[kt], a1B);
        }

        // ---- W3 loads here (wf regs dying): used after B2, well covered ----
        u16x8 w3A[4], w3B[4];
        {
            const unsigned short* p3A = w3base + (size_t)s0 * 8192;
            const unsigned short* p3B = w3base + (size_t)s1 * 8192;
            #pragma unroll
            for (int nt = 0; nt < 4; ++nt) {
                w3A[nt] = *(const u16x8*)(p3A + nt * 512);
                w3B[nt] = *(const u16x8*)(p3B + nt * 512);
            }
        }

        // ---- G1 epilogues: relu+bias, pack 4 feats -> one b64 per expert ----
        {
            u16x4 pkA, pkB;
            #pragma unroll
            for (int rg = 0; rg < 4; ++rg) {
                pkA[rg] = f2bf(fmaxf(a1A[rg] + bb1A[rg], 0.f));
                pkB[rg] = f2bf(fmaxf(a1B[rg] + bb1B[rg], 0.f));
            }
            int row = wm*16 + n15;
            *(u16x4*)&H1T[0][row * PH1 + wn*16 + q*4] = pkA;
            *(u16x4*)&H1T[1][row * PH1 + wn*16 + q*4] = pkB;
        }
        __syncthreads();                    // B1: h1 for both experts ready

        // ---- G2: wave handles ITS expert (wm), quadrant (r2,f2):
        //      lane -> h2 feats f2*16+q*4+rg, rows r2*16+n15 ----
        {
            f32x4 a2 = Z4;
            int hrow = r2*16 + n15;
            u16x8 h0 = *(const u16x8*)&H1T[wm][hrow * PH1 + q*8];
            u16x8 h1 = *(const u16x8*)&H1T[wm][hrow * PH1 + q*8 + 32];
            a2 = mfma16(w2f[0], h0, a2);
            a2 = mfma16(w2f[1], h1, a2);
            float sw = SWlds[hrow * PSW + e0 + wm];
            u16x4 pk;
            #pragma unroll
            for (int rg = 0; rg < 4; ++rg)
                pk[rg] = f2bf(fmaxf(a2[rg] + bb2[rg], 0.f) * sw);
            *(u16x4*)&H2T[wm][hrow * PH2 + f2*16 + q*4] = pk;
        }
        __syncthreads();                    // B2: h2 for both experts ready

        // ---- G3 both experts: ACC += h2 @ W3^T (4 independent chains) ----
        {
            u16x8 hA = *(const u16x8*)&H2T[0][(wm*16 + n15) * PH2 + q*8];
            u16x8 hB = *(const u16x8*)&H2T[1][(wm*16 + n15) * PH2 + q*8];
            #pragma unroll
            for (int nt = 0; nt < 4; ++nt)
                ACC[nt] = mfma16(hA, w3A[nt], ACC[nt]);
            #pragma unroll
            for (int nt = 0; nt < 4; ++nt)
                ACC[nt] = mfma16(hB, w3B[nt], ACC[nt]);
        }

        // ---- layer transition (e1 == 7 always lands at superstep end) ----
        if ((ss & 3) == 3 && l < LNUM - 1) {
            x_write();
            __syncthreads();
            xf_read();
            stage_softmax(l + 1);
            __syncthreads();
            acc_init(l + 1);
        }
    }

    // ================= final store (fp32) =================
    #pragma unroll
    for (int nt = 0; nt < 4; ++nt)
        #pragma unroll
        for (int rg = 0; rg < 4; ++rg)
            out[(size_t)(b0 + wm*16 + q*4 + rg) * DDIM
                + wn*64 + nt*16 + n15] = ACC[nt][rg];
}

extern "C" void kernel_launch(void* const* d_in, const int* in_sizes, int n_in,
                              void* d_out, int out_size, void* d_ws, size_t ws_size,
                              hipStream_t stream) {
    const float* src   = (const float*)d_in[0];
    const float* W1    = (const float*)d_in[1];
    const float* b1    = (const float*)d_in[2];
    const float* W2    = (const float*)d_in[3];
    const float* b2    = (const float*)d_in[4];
    const float* W3    = (const float*)d_in[5];
    const float* b3    = (const float*)d_in[6];
    const float* masks = (const float*)d_in[7];
    float* out = (float*)d_out;
    unsigned short* ws = (unsigned short*)d_ws;   // needs 3,407,872 B

    hipLaunchKernelGGL(cvt_w_frag, dim3(832), dim3(256), 0, stream, W1, W2, W3, ws);
    hipLaunchKernelGGL(moe_fused, dim3(BSZ / BT), dim3(NTHR), 0, stream,
                       src, ws, b1, b2, b3, masks, out);
}

// Round 2
// 200.439 us; speedup vs baseline: 1.2208x; 1.2208x over previous
//
#include <hip/hip_runtime.h>
#include <hip/hip_bf16.h>

// Problem constants
#define LNUM 8
#define ENUM 8
#define DDIM 256
#define BSZ  16384
#define H1N  64
#define H2N  32

#define BT   64     // rows per block
#define NTHR 512    // 8 waves

// LDS pitches (u16 elements); odd 16B-granule strides -> conflict-light
#define PX   264    // x tile (D + 8)
#define PH1  72     // h1T tile (H1 + 8)   [row][feat]
#define PH2  40     // h2T tile (H2 + 8)   [row][feat]
#define PSW  9      // softmax weights pitch (floats)

// ws element offsets (u16 elems) for fragment-ordered weights
#define WS1_OFF 0           // 64 steps * 16384 elems
#define WS2_OFF 1048576     // 64 steps * 2048
#define WS3_OFF 1179648     // 64 steps * 8192

typedef float f32x4 __attribute__((ext_vector_type(4)));
typedef unsigned short u16x8 __attribute__((ext_vector_type(8)));
typedef unsigned short u16x4 __attribute__((ext_vector_type(4)));
typedef __bf16 bf16x8 __attribute__((ext_vector_type(8)));

#define Z4 ((f32x4){0.f, 0.f, 0.f, 0.f})

// Round-to-nearest-even f32 -> bf16 (truncation bias compounds over 24 GEMMs).
static __device__ __forceinline__ unsigned short f2bf(float f) {
    unsigned u = __builtin_bit_cast(unsigned, f);
    u += 0x7fffu + ((u >> 16) & 1u);
    return (unsigned short)(u >> 16);
}

// D[m][n] = sum_k A[m][k]*B[n][k] + C : A supplies m, B supplies n, frags are
// symmetric [idx16][K] -> swapping args transposes the output tile.
static __device__ __forceinline__ f32x4 mfma16(u16x8 a, u16x8 b, f32x4 c) {
    return __builtin_amdgcn_mfma_f32_16x16x32_bf16(
        __builtin_bit_cast(bf16x8, a), __builtin_bit_cast(bf16x8, b), c, 0, 0, 0);
}

// Barrier with lgkmcnt-only drain: LDS producer/consumer ordering preserved,
// but in-flight GLOBAL loads (weight prefetch) are NOT drained (vs
// __syncthreads which emits s_waitcnt vmcnt(0)). Safe here: all inter-wave
// data flows through LDS; no global stores inside the loop.
static __device__ __forceinline__ void lbar() {
    asm volatile("s_waitcnt lgkmcnt(0)" ::: "memory");
    __builtin_amdgcn_s_barrier();
    asm volatile("" ::: "memory");
}

// ---------------------------------------------------------------------------
// Kernel 1: fp32 weights -> bf16 B-fragment layout. Coalesced reads,
// scattered 16B fragment writes (L2 merges).
// Fragment: 64 lanes x 8 elems; slot (q*16+r) holds W[n0+r][k0+q*8 .. +7].
// ---------------------------------------------------------------------------
__global__ __launch_bounds__(256) void cvt_w_frag(
    const float* __restrict__ w1, const float* __restrict__ w2,
    const float* __restrict__ w3, unsigned short* __restrict__ ws)
{
    int gid = blockIdx.x * 256 + threadIdx.x;
    const float* src;
    unsigned short* dst;
    if (gid < 131072) {                          // W1: [s][n(64)][k(256)]
        int s = gid >> 11, rem = gid & 2047;
        int n = rem >> 5, kc = rem & 31;
        int nt = n >> 4, r = n & 15, kt = kc >> 2, q = kc & 3;
        src = w1 + (size_t)gid * 8;
        dst = ws + WS1_OFF + (size_t)s * 16384 + nt * 4096 + kt * 512 + (q * 16 + r) * 8;
    } else if (gid < 147456) {                   // W2: [s][n(32)][k(64)]
        int g = gid - 131072;
        int s = g >> 8, rem = g & 255;
        int n = rem >> 3, kc = rem & 7;
        int n2 = n >> 4, r = n & 15, kt = kc >> 2, q = kc & 3;
        src = w2 + (size_t)g * 8;
        dst = ws + WS2_OFF + (size_t)s * 2048 + n2 * 1024 + kt * 512 + (q * 16 + r) * 8;
    } else {                                     // W3: [s][n(256)][k(32)]
        int g = gid - 147456;
        int s = g >> 10, rem = g & 1023;
        int n = rem >> 2, q = rem & 3;
        int nt = n >> 4, r = n & 15;
        src = w3 + (size_t)g * 8;
        dst = ws + WS3_OFF + (size_t)s * 8192 + nt * 512 + (q * 16 + r) * 8;
    }
    float4 a = *(const float4*)src;
    float4 b = *(const float4*)(src + 4);
    u16x8 p;
    p[0] = f2bf(a.x); p[1] = f2bf(a.y); p[2] = f2bf(a.z); p[3] = f2bf(a.w);
    p[4] = f2bf(b.x); p[5] = f2bf(b.y); p[6] = f2bf(b.z); p[7] = f2bf(b.w);
    *(u16x8*)dst = p;
}

// ---------------------------------------------------------------------------
// Kernel 2: fused 8-layer x 8-expert MoE MLP, 2-expert supersteps.
// Round-0 geometry (BT=64, 8 waves, 4-chain G1) + software pipelining:
//  - W1/W2 loads rotated one superstep ahead (issued right after last use),
//  - lgkmcnt-only barriers so weight loads stay in flight across B1/B2.
// Grid-capped at 1 block/CU (2 waves/SIMD) -> VGPRs up to 256 are free.
// ---------------------------------------------------------------------------
__global__ __launch_bounds__(NTHR, 2) void moe_fused(
    const float* __restrict__ src, const unsigned short* __restrict__ Wf,
    const float* __restrict__ b1, const float* __restrict__ b2,
    const float* __restrict__ b3, const float* __restrict__ masks,
    float* __restrict__ out)
{
    __shared__ __align__(16) unsigned short Xlds[BT * PX];        // 33792 B
    __shared__ __align__(16) unsigned short H1T[2][BT * PH1];     // 18432 B [row][feat]
    __shared__ __align__(16) unsigned short H2T[2][BT * PH2];     // 10240 B [row][feat]
    __shared__ float SWlds[BT * PSW];                             //  2304 B
    // total 64768 B

    const int tid  = threadIdx.x;
    const int lane = tid & 63;
    const int w    = tid >> 6;
    const int wm   = w >> 2;        // {0,1}
    const int wn   = w & 3;         // {0..3}
    const int n15  = lane & 15;
    const int q    = lane >> 4;
    const int b0   = blockIdx.x * BT;

    const unsigned short* w1base = Wf + WS1_OFF + wn * 4096 + lane * 8;  // feat grp wn
    const unsigned short* w2base = Wf + WS2_OFF + wm * 1024 + lane * 8;  // feat grp wm
    const unsigned short* w3base = Wf + WS3_OFF + wn * 2048 + lane * 8;  // out grp wn

    u16x8 xf[2][8];          // persistent x B-frags: rows wm*32+mt*16, K=256
    f32x4 ACC[2][4];         // output accumulator (C-layout: row=q*4+rg, col=n15)
    u16x8 wfA[8], wfB[8];    // W1 frags, rotated (loaded one superstep ahead)
    u16x8 w2A[2], w2B[2];    // W2 frags, rotated

    auto stage_softmax = [&](int l) {
        if (tid < 64) {
            const float* mp = masks + ((size_t)l * BSZ + b0 + tid) * ENUM;
            float4 m0 = *(const float4*)mp;
            float4 m1 = *(const float4*)(mp + 4);
            float mv[8] = {m0.x, m0.y, m0.z, m0.w, m1.x, m1.y, m1.z, m1.w};
            float mx = mv[0];
            #pragma unroll
            for (int e = 1; e < 8; ++e) mx = fmaxf(mx, mv[e]);
            float s = 0.f;
            #pragma unroll
            for (int e = 0; e < 8; ++e) { mv[e] = expf(mv[e] - mx); s += mv[e]; }
            float inv = 1.f / s;
            #pragma unroll
            for (int e = 0; e < 8; ++e) SWlds[tid * PSW + e] = mv[e] * inv;
        }
    };

    // ACC = sum_e softmax_w[row][e] * b3[e][col]  (fp32 VALU, once per layer)
    auto acc_init = [&](int l) {
        const float* b3l = b3 + (size_t)l * ENUM * DDIM;
        #pragma unroll
        for (int mt = 0; mt < 2; ++mt)
            #pragma unroll
            for (int nt = 0; nt < 4; ++nt) ACC[mt][nt] = Z4;
        #pragma unroll 2
        for (int e2 = 0; e2 < ENUM; ++e2) {
            float swv[2][4];
            #pragma unroll
            for (int mt = 0; mt < 2; ++mt)
                #pragma unroll
                for (int rg = 0; rg < 4; ++rg)
                    swv[mt][rg] = SWlds[(wm*32 + mt*16 + q*4 + rg) * PSW + e2];
            #pragma unroll
            for (int nt = 0; nt < 4; ++nt) {
                float bv = b3l[e2 * DDIM + wn*64 + nt*16 + n15];
                #pragma unroll
                for (int mt = 0; mt < 2; ++mt)
                    #pragma unroll
                    for (int rg = 0; rg < 4; ++rg)
                        ACC[mt][nt][rg] += swv[mt][rg] * bv;
            }
        }
    };

    auto xf_read = [&]() {
        #pragma unroll
        for (int mt = 0; mt < 2; ++mt)
            #pragma unroll
            for (int kt = 0; kt < 8; ++kt)
                xf[mt][kt] = *(const u16x8*)
                    &Xlds[(wm*32 + mt*16 + n15) * PX + q*8 + kt*32];
    };
    auto x_write = [&]() {
        #pragma unroll
        for (int mt = 0; mt < 2; ++mt)
            #pragma unroll
            for (int nt = 0; nt < 4; ++nt)
                #pragma unroll
                for (int rg = 0; rg < 4; ++rg)
                    Xlds[(wm*32 + mt*16 + q*4 + rg) * PX + wn*64 + nt*16 + n15] =
                        f2bf(ACC[mt][nt][rg]);
    };

    // ================= prologue =================
    #pragma unroll
    for (int i = 0; i < 4; ++i) {                // stage layer-0 x (bf16)
        int o = (i * NTHR + tid) * 8;
        int r = o >> 8, c = o & 255;
        const float* p = src + (size_t)(b0 + r) * DDIM + c;
        float4 f0 = *(const float4*)(p);
        float4 f1 = *(const float4*)(p + 4);
        u16x8 pk;
        pk[0] = f2bf(f0.x); pk[1] = f2bf(f0.y); pk[2] = f2bf(f0.z); pk[3] = f2bf(f0.w);
        pk[4] = f2bf(f1.x); pk[5] = f2bf(f1.y); pk[6] = f2bf(f1.z); pk[7] = f2bf(f1.w);
        *(u16x8*)&Xlds[r * PX + c] = pk;
    }
    stage_softmax(0);

    // Pre-load superstep 0's W1/W2 (rotation prologue); in flight across the
    // staging barrier below (lbar does not drain vmcnt).
    {
        const unsigned short* pA = w1base;                 // s=0
        const unsigned short* pB = w1base + 16384;         // s=1
        #pragma unroll
        for (int kt = 0; kt < 8; ++kt) {
            wfA[kt] = *(const u16x8*)(pA + kt * 512);
            wfB[kt] = *(const u16x8*)(pB + kt * 512);
        }
        const unsigned short* q2A = w2base;                // s=0
        const unsigned short* q2B = w2base + 2048;         // s=1
        w2A[0] = *(const u16x8*)(q2A);  w2A[1] = *(const u16x8*)(q2A + 512);
        w2B[0] = *(const u16x8*)(q2B);  w2B[1] = *(const u16x8*)(q2B + 512);
    }
    lbar();
    xf_read();
    acc_init(0);

    // ================= superstep loop: 2 experts per iteration =================
    #pragma unroll 1
    for (int ss = 0; ss < LNUM * ENUM / 2; ++ss) {
        const int s0 = 2 * ss, s1 = s0 + 1;
        const int l  = s0 >> 3, e0 = s0 & 7, e1 = s1 & 7;

        // biases for current superstep (first use ~1 G1-phase away)
        const float4 bb1A = *(const float4*)(b1 + s0 * 64 + wn * 16 + q * 4);
        const float4 bb1B = *(const float4*)(b1 + s1 * 64 + wn * 16 + q * 4);
        const float4 bb2A = *(const float4*)(b2 + s0 * 32 + wm * 16 + q * 4);
        const float4 bb2B = *(const float4*)(b2 + s1 * 32 + wm * 16 + q * 4);

        // ---- G1 both experts (transposed): lane -> feats wn*16+q*4+rg ----
        // 4 independent chains; B-frag xf shared by both experts.
        // wfA/wfB were loaded one superstep ago (or in the prologue).
        f32x4 a1A[2] = {Z4, Z4}, a1B[2] = {Z4, Z4};
        #pragma unroll
        for (int kt = 0; kt < 8; ++kt) {
            a1A[0] = mfma16(wfA[kt], xf[0][kt], a1A[0]);
            a1A[1] = mfma16(wfA[kt], xf[1][kt], a1A[1]);
            a1B[0] = mfma16(wfB[kt], xf[0][kt], a1B[0]);
            a1B[1] = mfma16(wfB[kt], xf[1][kt], a1B[1]);
        }

        // ---- W3 loads (current ss): used after B2, covered by G1-epi+G2 ----
        u16x8 w3A[4], w3B[4];
        {
            const unsigned short* p3A = w3base + (size_t)s0 * 8192;
            const unsigned short* p3B = w3base + (size_t)s1 * 8192;
            #pragma unroll
            for (int nt = 0; nt < 4; ++nt) {
                w3A[nt] = *(const u16x8*)(p3A + nt * 512);
                w3B[nt] = *(const u16x8*)(p3B + nt * 512);
            }
        }

        // ---- NEXT-superstep W1 loads (wfA/wfB just died in G1 above).
        // Used at next iteration's G1: in flight across B1, G2, B2, G3.
        // Tail over-read (ss=31) stays inside the ws buffer, values unused.
        {
            const unsigned short* pA = w1base + (size_t)(s0 + 2) * 16384;
            const unsigned short* pB = w1base + (size_t)(s1 + 2) * 16384;
            #pragma unroll
            for (int kt = 0; kt < 8; ++kt) {
                wfA[kt] = *(const u16x8*)(pA + kt * 512);
                wfB[kt] = *(const u16x8*)(pB + kt * 512);
            }
        }

        // ---- G1 epilogues: relu+bias, pack 4 feats -> one b64 per (mt,expert) ----
        #pragma unroll
        for (int mt = 0; mt < 2; ++mt) {
            u16x4 pkA, pkB;
            #pragma unroll
            for (int rg = 0; rg < 4; ++rg) {
                pkA[rg] = f2bf(fmaxf(a1A[mt][rg] + bb1A[rg], 0.f));
                pkB[rg] = f2bf(fmaxf(a1B[mt][rg] + bb1B[rg], 0.f));
            }
            int row = wm*32 + mt*16 + n15;
            *(u16x4*)&H1T[0][row * PH1 + wn*16 + q*4] = pkA;
            *(u16x4*)&H1T[1][row * PH1 + wn*16 + q*4] = pkB;
        }
        lbar();                             // B1: h1 ready; W1/W3 stay in flight

        // ---- G2 both experts (transposed): lane -> h2 feats wm*16+q*4+rg,
        //      row group wn ----
        f32x4 a2A = Z4, a2B = Z4;
        {
            u16x8 hA0 = *(const u16x8*)&H1T[0][(wn*16 + n15) * PH1 + q*8];
            u16x8 hA1 = *(const u16x8*)&H1T[0][(wn*16 + n15) * PH1 + q*8 + 32];
            u16x8 hB0 = *(const u16x8*)&H1T[1][(wn*16 + n15) * PH1 + q*8];
            u16x8 hB1 = *(const u16x8*)&H1T[1][(wn*16 + n15) * PH1 + q*8 + 32];
            a2A = mfma16(w2A[0], hA0, a2A);
            a2B = mfma16(w2B[0], hB0, a2B);
            a2A = mfma16(w2A[1], hA1, a2A);
            a2B = mfma16(w2B[1], hB1, a2B);
        }

        // ---- NEXT-superstep W2 loads (w2A/w2B just died above) ----
        {
            const unsigned short* q2A = w2base + (size_t)(s0 + 2) * 2048;
            const unsigned short* q2B = w2base + (size_t)(s1 + 2) * 2048;
            w2A[0] = *(const u16x8*)(q2A);  w2A[1] = *(const u16x8*)(q2A + 512);
            w2B[0] = *(const u16x8*)(q2B);  w2B[1] = *(const u16x8*)(q2B + 512);
        }

        {
            int row = wn*16 + n15;
            float swA = SWlds[row * PSW + e0];
            float swB = SWlds[row * PSW + e1];
            u16x4 pkA, pkB;
            #pragma unroll
            for (int rg = 0; rg < 4; ++rg) {
                pkA[rg] = f2bf(fmaxf(a2A[rg] + bb2A[rg], 0.f) * swA);
                pkB[rg] = f2bf(fmaxf(a2B[rg] + bb2B[rg], 0.f) * swB);
            }
            *(u16x4*)&H2T[0][row * PH2 + wm*16 + q*4] = pkA;
            *(u16x4*)&H2T[1][row * PH2 + wm*16 + q*4] = pkB;
        }
        lbar();                             // B2: h2 ready; W1/W2 stay in flight

        // ---- G3 both experts: ACC += h2 @ W3^T (8 independent chains) ----
        {
            u16x8 hA0 = *(const u16x8*)&H2T[0][(wm*32 + n15) * PH2 + q*8];
            u16x8 hA1 = *(const u16x8*)&H2T[0][(wm*32 + 16 + n15) * PH2 + q*8];
            u16x8 hB0 = *(const u16x8*)&H2T[1][(wm*32 + n15) * PH2 + q*8];
            u16x8 hB1 = *(const u16x8*)&H2T[1][(wm*32 + 16 + n15) * PH2 + q*8];
            #pragma unroll
            for (int nt = 0; nt < 4; ++nt) {
                ACC[0][nt] = mfma16(hA0, w3A[nt], ACC[0][nt]);
                ACC[1][nt] = mfma16(hA1, w3A[nt], ACC[1][nt]);
            }
            #pragma unroll
            for (int nt = 0; nt < 4; ++nt) {
                ACC[0][nt] = mfma16(hB0, w3B[nt], ACC[0][nt]);
                ACC[1][nt] = mfma16(hB1, w3B[nt], ACC[1][nt]);
            }
        }

        // ---- layer transition (e1 == 7 always lands at superstep end) ----
        if (e1 == 7 && l < LNUM - 1) {
            x_write();
            lbar();
            xf_read();
            stage_softmax(l + 1);
            lbar();
            acc_init(l + 1);
        }
    }

    // ================= final store (fp32) =================
    #pragma unroll
    for (int mt = 0; mt < 2; ++mt)
        #pragma unroll
        for (int nt = 0; nt < 4; ++nt)
            #pragma unroll
            for (int rg = 0; rg < 4; ++rg)
                out[(size_t)(b0 + wm*32 + mt*16 + q*4 + rg) * DDIM
                    + wn*64 + nt*16 + n15] = ACC[mt][nt][rg];
}

extern "C" void kernel_launch(void* const* d_in, const int* in_sizes, int n_in,
                              void* d_out, int out_size, void* d_ws, size_t ws_size,
                              hipStream_t stream) {
    const float* src   = (const float*)d_in[0];
    const float* W1    = (const float*)d_in[1];
    const float* b1    = (const float*)d_in[2];
    const float* W2    = (const float*)d_in[3];
    const float* b2    = (const float*)d_in[4];
    const float* W3    = (const float*)d_in[5];
    const float* b3    = (const float*)d_in[6];
    const float* masks = (const float*)d_in[7];
    float* out = (float*)d_out;
    unsigned short* ws = (unsigned short*)d_ws;   // needs 3,407,872 B

    hipLaunchKernelGGL(cvt_w_frag, dim3(832), dim3(256), 0, stream, W1, W2, W3, ws);
    hipLaunchKernelGGL(moe_fused, dim3(BSZ / BT), dim3(NTHR), 0, stream,
                       src, ws, b1, b2, b3, masks, out);
}

// Round 3
// 181.771 us; speedup vs baseline: 1.3462x; 1.1027x over previous
//
#include <hip/hip_runtime.h>
#include <hip/hip_bf16.h>

// Problem constants
#define LNUM 8
#define ENUM 8
#define DDIM 256
#define BSZ  16384
#define H1N  64
#define H2N  32

#define BT   32     // rows per block  (grid 512 -> 2 independent blocks/CU)
#define NTHR 256    // 4 waves         (per-wave work shape IDENTICAL to R0)

// LDS pitches (u16 elements); odd 16B-granule strides -> conflict-light
#define PX   264    // x tile (D + 8)
#define PH1  72     // h1T tile (H1 + 8)   [row][feat]
#define PH2  40     // h2T tile (H2 + 8)   [row][feat]
#define PSW  9      // softmax weights pitch (floats)

// ws element offsets (u16 elems) for fragment-ordered weights
#define WS1_OFF 0           // 64 steps * 16384 elems
#define WS2_OFF 1048576     // 64 steps * 2048
#define WS3_OFF 1179648     // 64 steps * 8192

typedef float f32x4 __attribute__((ext_vector_type(4)));
typedef unsigned short u16x8 __attribute__((ext_vector_type(8)));
typedef unsigned short u16x4 __attribute__((ext_vector_type(4)));
typedef __bf16 bf16x8 __attribute__((ext_vector_type(8)));

#define Z4 ((f32x4){0.f, 0.f, 0.f, 0.f})

// Round-to-nearest-even f32 -> bf16 (truncation bias compounds over 24 GEMMs).
static __device__ __forceinline__ unsigned short f2bf(float f) {
    unsigned u = __builtin_bit_cast(unsigned, f);
    u += 0x7fffu + ((u >> 16) & 1u);
    return (unsigned short)(u >> 16);
}

// D[m][n] = sum_k A[m][k]*B[n][k] + C : A supplies m, B supplies n, frags are
// symmetric [idx16][K] -> swapping args transposes the output tile.
static __device__ __forceinline__ f32x4 mfma16(u16x8 a, u16x8 b, f32x4 c) {
    return __builtin_amdgcn_mfma_f32_16x16x32_bf16(
        __builtin_bit_cast(bf16x8, a), __builtin_bit_cast(bf16x8, b), c, 0, 0, 0);
}

// ---------------------------------------------------------------------------
// Kernel 1: fp32 weights -> bf16 B-fragment layout. Coalesced reads,
// scattered 16B fragment writes (L2 merges). Unchanged.
// Fragment: 64 lanes x 8 elems; slot (q*16+r) holds W[n0+r][k0+q*8 .. +7].
// ---------------------------------------------------------------------------
__global__ __launch_bounds__(256) void cvt_w_frag(
    const float* __restrict__ w1, const float* __restrict__ w2,
    const float* __restrict__ w3, unsigned short* __restrict__ ws)
{
    int gid = blockIdx.x * 256 + threadIdx.x;
    const float* src;
    unsigned short* dst;
    if (gid < 131072) {                          // W1: [s][n(64)][k(256)]
        int s = gid >> 11, rem = gid & 2047;
        int n = rem >> 5, kc = rem & 31;
        int nt = n >> 4, r = n & 15, kt = kc >> 2, q = kc & 3;
        src = w1 + (size_t)gid * 8;
        dst = ws + WS1_OFF + (size_t)s * 16384 + nt * 4096 + kt * 512 + (q * 16 + r) * 8;
    } else if (gid < 147456) {                   // W2: [s][n(32)][k(64)]
        int g = gid - 131072;
        int s = g >> 8, rem = g & 255;
        int n = rem >> 3, kc = rem & 7;
        int n2 = n >> 4, r = n & 15, kt = kc >> 2, q = kc & 3;
        src = w2 + (size_t)g * 8;
        dst = ws + WS2_OFF + (size_t)s * 2048 + n2 * 1024 + kt * 512 + (q * 16 + r) * 8;
    } else {                                     // W3: [s][n(256)][k(32)]
        int g = gid - 147456;
        int s = g >> 10, rem = g & 1023;
        int n = rem >> 2, q = rem & 3;
        int nt = n >> 4, r = n & 15;
        src = w3 + (size_t)g * 8;
        dst = ws + WS3_OFF + (size_t)s * 8192 + nt * 512 + (q * 16 + r) * 8;
    }
    float4 a = *(const float4*)src;
    float4 b = *(const float4*)(src + 4);
    u16x8 p;
    p[0] = f2bf(a.x); p[1] = f2bf(a.y); p[2] = f2bf(a.z); p[3] = f2bf(a.w);
    p[4] = f2bf(b.x); p[5] = f2bf(b.y); p[6] = f2bf(b.z); p[7] = f2bf(b.w);
    *(u16x8*)dst = p;
}

// ---------------------------------------------------------------------------
// Kernel 2: fused 8-layer x 8-expert MoE MLP, 2-expert supersteps.
// R0's per-wave schedule EXACTLY (52 MFMA/wave/superstep, same load
// placement, __syncthreads barriers) but in a 4-wave / 32-row block:
// grid 512 -> 2 independent barrier domains per CU at the same 8 waves/CU,
// so one block's MFMAs cover the other block's barrier + L2-latency stalls.
// Wave roles: wn = feat grp (G1) / col grp (G3); G2 tile = (rg,fg) =
// (wn&1, wn>>1), both experts per wave.
// ---------------------------------------------------------------------------
__global__ __launch_bounds__(NTHR, 2) void moe_fused(
    const float* __restrict__ src, const unsigned short* __restrict__ Wf,
    const float* __restrict__ b1, const float* __restrict__ b2,
    const float* __restrict__ b3, const float* __restrict__ masks,
    float* __restrict__ out)
{
    __shared__ __align__(16) unsigned short Xlds[BT * PX];        // 16896 B
    __shared__ __align__(16) unsigned short H1T[2][BT * PH1];     //  9216 B [row][feat]
    __shared__ __align__(16) unsigned short H2T[2][BT * PH2];     //  5120 B [row][feat]
    __shared__ float SWlds[BT * PSW];                             //  1152 B
    // total 32384 B -> 2 blocks/CU fit easily

    const int tid  = threadIdx.x;
    const int lane = tid & 63;
    const int wn   = tid >> 6;      // {0..3}: feat grp (G1), col grp (G3)
    const int rg   = wn & 1;        // G2 row group
    const int fg   = wn >> 1;       // G2 feat group
    const int n15  = lane & 15;
    const int q    = lane >> 4;
    const int b0   = blockIdx.x * BT;

    const unsigned short* w1base = Wf + WS1_OFF + wn * 4096 + lane * 8;  // feat grp wn
    const unsigned short* w2base = Wf + WS2_OFF + fg * 1024 + lane * 8;  // feat grp fg
    const unsigned short* w3base = Wf + WS3_OFF + wn * 2048 + lane * 8;  // out grp wn

    u16x8 xf[2][8];          // persistent x B-frags: rows mt*16, K=256
    f32x4 ACC[2][4];         // output accumulator (C-layout: row=q*4+rg, col=n15)

    auto stage_softmax = [&](int l) {
        if (tid < BT) {
            const float* mp = masks + ((size_t)l * BSZ + b0 + tid) * ENUM;
            float4 m0 = *(const float4*)mp;
            float4 m1 = *(const float4*)(mp + 4);
            float mv[8] = {m0.x, m0.y, m0.z, m0.w, m1.x, m1.y, m1.z, m1.w};
            float mx = mv[0];
            #pragma unroll
            for (int e = 1; e < 8; ++e) mx = fmaxf(mx, mv[e]);
            float s = 0.f;
            #pragma unroll
            for (int e = 0; e < 8; ++e) { mv[e] = expf(mv[e] - mx); s += mv[e]; }
            float inv = 1.f / s;
            #pragma unroll
            for (int e = 0; e < 8; ++e) SWlds[tid * PSW + e] = mv[e] * inv;
        }
    };

    // ACC = sum_e softmax_w[row][e] * b3[e][col]  (fp32 VALU, once per layer)
    auto acc_init = [&](int l) {
        const float* b3l = b3 + (size_t)l * ENUM * DDIM;
        #pragma unroll
        for (int mt = 0; mt < 2; ++mt)
            #pragma unroll
            for (int nt = 0; nt < 4; ++nt) ACC[mt][nt] = Z4;
        #pragma unroll 2
        for (int e2 = 0; e2 < ENUM; ++e2) {
            float swv[2][4];
            #pragma unroll
            for (int mt = 0; mt < 2; ++mt)
                #pragma unroll
                for (int rr = 0; rr < 4; ++rr)
                    swv[mt][rr] = SWlds[(mt*16 + q*4 + rr) * PSW + e2];
            #pragma unroll
            for (int nt = 0; nt < 4; ++nt) {
                float bv = b3l[e2 * DDIM + wn*64 + nt*16 + n15];
                #pragma unroll
                for (int mt = 0; mt < 2; ++mt)
                    #pragma unroll
                    for (int rr = 0; rr < 4; ++rr)
                        ACC[mt][nt][rr] += swv[mt][rr] * bv;
            }
        }
    };

    auto xf_read = [&]() {
        #pragma unroll
        for (int mt = 0; mt < 2; ++mt)
            #pragma unroll
            for (int kt = 0; kt < 8; ++kt)
                xf[mt][kt] = *(const u16x8*)
                    &Xlds[(mt*16 + n15) * PX + q*8 + kt*32];
    };
    auto x_write = [&]() {
        #pragma unroll
        for (int mt = 0; mt < 2; ++mt)
            #pragma unroll
            for (int nt = 0; nt < 4; ++nt)
                #pragma unroll
                for (int rr = 0; rr < 4; ++rr)
                    Xlds[(mt*16 + q*4 + rr) * PX + wn*64 + nt*16 + n15] =
                        f2bf(ACC[mt][nt][rr]);
    };

    // ================= prologue =================
    #pragma unroll
    for (int i = 0; i < 4; ++i) {                // stage layer-0 x (bf16)
        int o = (i * NTHR + tid) * 8;
        int r = o >> 8, c = o & 255;
        const float* p = src + (size_t)(b0 + r) * DDIM + c;
        float4 f0 = *(const float4*)(p);
        float4 f1 = *(const float4*)(p + 4);
        u16x8 pk;
        pk[0] = f2bf(f0.x); pk[1] = f2bf(f0.y); pk[2] = f2bf(f0.z); pk[3] = f2bf(f0.w);
        pk[4] = f2bf(f1.x); pk[5] = f2bf(f1.y); pk[6] = f2bf(f1.z); pk[7] = f2bf(f1.w);
        *(u16x8*)&Xlds[r * PX + c] = pk;
    }
    stage_softmax(0);
    __syncthreads();
    xf_read();
    acc_init(0);

    // ================= superstep loop: 2 experts per iteration =================
    #pragma unroll 1
    for (int ss = 0; ss < LNUM * ENUM / 2; ++ss) {
        const int s0 = 2 * ss, s1 = s0 + 1;
        const int l  = s0 >> 3, e0 = s0 & 7, e1 = s1 & 7;

        // ---- superstep-top loads: W1 both experts, W2 both, biases ----
        u16x8 wfA[8], wfB[8], w2A[2], w2B[2];
        {
            const unsigned short* pA = w1base + (size_t)s0 * 16384;
            const unsigned short* pB = w1base + (size_t)s1 * 16384;
            #pragma unroll
            for (int kt = 0; kt < 8; ++kt) {
                wfA[kt] = *(const u16x8*)(pA + kt * 512);
                wfB[kt] = *(const u16x8*)(pB + kt * 512);
            }
            const unsigned short* q2A = w2base + (size_t)s0 * 2048;
            const unsigned short* q2B = w2base + (size_t)s1 * 2048;
            w2A[0] = *(const u16x8*)(q2A);  w2A[1] = *(const u16x8*)(q2A + 512);
            w2B[0] = *(const u16x8*)(q2B);  w2B[1] = *(const u16x8*)(q2B + 512);
        }
        const float4 bb1A = *(const float4*)(b1 + s0 * 64 + wn * 16 + q * 4);
        const float4 bb1B = *(const float4*)(b1 + s1 * 64 + wn * 16 + q * 4);
        const float4 bb2A = *(const float4*)(b2 + s0 * 32 + fg * 16 + q * 4);
        const float4 bb2B = *(const float4*)(b2 + s1 * 32 + fg * 16 + q * 4);

        // ---- G1 both experts (transposed): lane -> feats wn*16+q*4+rr ----
        // 4 independent chains; B-frag xf shared by both experts.
        f32x4 a1A[2] = {Z4, Z4}, a1B[2] = {Z4, Z4};
        #pragma unroll
        for (int kt = 0; kt < 8; ++kt) {
            a1A[0] = mfma16(wfA[kt], xf[0][kt], a1A[0]);
            a1A[1] = mfma16(wfA[kt], xf[1][kt], a1A[1]);
            a1B[0] = mfma16(wfB[kt], xf[0][kt], a1B[0]);
            a1B[1] = mfma16(wfB[kt], xf[1][kt], a1B[1]);
        }

        // ---- W3 loads here (wf regs dead): used after B2, well covered ----
        u16x8 w3A[4], w3B[4];
        {
            const unsigned short* p3A = w3base + (size_t)s0 * 8192;
            const unsigned short* p3B = w3base + (size_t)s1 * 8192;
            #pragma unroll
            for (int nt = 0; nt < 4; ++nt) {
                w3A[nt] = *(const u16x8*)(p3A + nt * 512);
                w3B[nt] = *(const u16x8*)(p3B + nt * 512);
            }
        }

        // ---- G1 epilogues: relu+bias, pack 4 feats -> one b64 per (mt,expert) ----
        #pragma unroll
        for (int mt = 0; mt < 2; ++mt) {
            u16x4 pkA, pkB;
            #pragma unroll
            for (int rr = 0; rr < 4; ++rr) {
                pkA[rr] = f2bf(fmaxf(a1A[mt][rr] + bb1A[rr], 0.f));
                pkB[rr] = f2bf(fmaxf(a1B[mt][rr] + bb1B[rr], 0.f));
            }
            int row = mt*16 + n15;
            *(u16x4*)&H1T[0][row * PH1 + wn*16 + q*4] = pkA;
            *(u16x4*)&H1T[1][row * PH1 + wn*16 + q*4] = pkB;
        }
        __syncthreads();                    // B1: h1 for both experts ready

        // ---- G2 both experts (transposed): lane -> h2 feats fg*16+q*4+rr,
        //      rows rg*16+n15 ----
        f32x4 a2A = Z4, a2B = Z4;
        {
            int hrow = rg*16 + n15;
            u16x8 hA0 = *(const u16x8*)&H1T[0][hrow * PH1 + q*8];
            u16x8 hA1 = *(const u16x8*)&H1T[0][hrow * PH1 + q*8 + 32];
            u16x8 hB0 = *(const u16x8*)&H1T[1][hrow * PH1 + q*8];
            u16x8 hB1 = *(const u16x8*)&H1T[1][hrow * PH1 + q*8 + 32];
            a2A = mfma16(w2A[0], hA0, a2A);
            a2B = mfma16(w2B[0], hB0, a2B);
            a2A = mfma16(w2A[1], hA1, a2A);
            a2B = mfma16(w2B[1], hB1, a2B);
        }
        {
            int row = rg*16 + n15;
            float swA = SWlds[row * PSW + e0];
            float swB = SWlds[row * PSW + e1];
            u16x4 pkA, pkB;
            #pragma unroll
            for (int rr = 0; rr < 4; ++rr) {
                pkA[rr] = f2bf(fmaxf(a2A[rr] + bb2A[rr], 0.f) * swA);
                pkB[rr] = f2bf(fmaxf(a2B[rr] + bb2B[rr], 0.f) * swB);
            }
            *(u16x4*)&H2T[0][row * PH2 + fg*16 + q*4] = pkA;
            *(u16x4*)&H2T[1][row * PH2 + fg*16 + q*4] = pkB;
        }
        __syncthreads();                    // B2: h2 for both experts ready

        // ---- G3 both experts: ACC += h2 @ W3^T (8 independent chains) ----
        {
            u16x8 hA0 = *(const u16x8*)&H2T[0][(n15) * PH2 + q*8];
            u16x8 hA1 = *(const u16x8*)&H2T[0][(16 + n15) * PH2 + q*8];
            u16x8 hB0 = *(const u16x8*)&H2T[1][(n15) * PH2 + q*8];
            u16x8 hB1 = *(const u16x8*)&H2T[1][(16 + n15) * PH2 + q*8];
            #pragma unroll
            for (int nt = 0; nt < 4; ++nt) {
                ACC[0][nt] = mfma16(hA0, w3A[nt], ACC[0][nt]);
                ACC[1][nt] = mfma16(hA1, w3A[nt], ACC[1][nt]);
            }
            #pragma unroll
            for (int nt = 0; nt < 4; ++nt) {
                ACC[0][nt] = mfma16(hB0, w3B[nt], ACC[0][nt]);
                ACC[1][nt] = mfma16(hB1, w3B[nt], ACC[1][nt]);
            }
        }

        // ---- layer transition (e1 == 7 always lands at superstep end) ----
        if (e1 == 7 && l < LNUM - 1) {
            x_write();
            __syncthreads();
            xf_read();
            stage_softmax(l + 1);
            __syncthreads();
            acc_init(l + 1);
        }
    }

    // ================= final store (fp32) =================
    #pragma unroll
    for (int mt = 0; mt < 2; ++mt)
        #pragma unroll
        for (int nt = 0; nt < 4; ++nt)
            #pragma unroll
            for (int rr = 0; rr < 4; ++rr)
                out[(size_t)(b0 + mt*16 + q*4 + rr) * DDIM
                    + wn*64 + nt*16 + n15] = ACC[mt][nt][rr];
}

extern "C" void kernel_launch(void* const* d_in, const int* in_sizes, int n_in,
                              void* d_out, int out_size, void* d_ws, size_t ws_size,
                              hipStream_t stream) {
    const float* src   = (const float*)d_in[0];
    const float* W1    = (const float*)d_in[1];
    const float* b1    = (const float*)d_in[2];
    const float* W2    = (const float*)d_in[3];
    const float* b2    = (const float*)d_in[4];
    const float* W3    = (const float*)d_in[5];
    const float* b3    = (const float*)d_in[6];
    const float* masks = (const float*)d_in[7];
    float* out = (float*)d_out;
    unsigned short* ws = (unsigned short*)d_ws;   // needs 3,407,872 B

    hipLaunchKernelGGL(cvt_w_frag, dim3(832), dim3(256), 0, stream, W1, W2, W3, ws);
    hipLaunchKernelGGL(moe_fused, dim3(BSZ / BT), dim3(NTHR), 0, stream,
                       src, ws, b1, b2, b3, masks, out);
}

// Round 4
// 178.138 us; speedup vs baseline: 1.3736x; 1.0204x over previous
//
#include <hip/hip_runtime.h>
#include <hip/hip_bf16.h>

// Problem constants
#define LNUM 8
#define ENUM 8
#define DDIM 256
#define BSZ  16384
#define H1N  64
#define H2N  32

#define BT   32     // rows per block  (grid 512 -> 2 independent blocks/CU)
#define NTHR 256    // 4 waves         (per-wave work shape IDENTICAL to R0/R3)

// LDS pitches (u16 elements); odd 16B-granule strides -> conflict-light
#define PX   264    // x tile (D + 8)
#define PH1  72     // h1T tile (H1 + 8)   [row][feat]
#define PH2  40     // h2T tile (H2 + 8)   [row][feat]
#define PSW  9      // softmax weights pitch (floats)

// ws element offsets (u16 elems) for fragment-ordered weights
#define WS1_OFF 0           // 64 steps * 16384 elems
#define WS2_OFF 1048576     // 64 steps * 2048
#define WS3_OFF 1179648     // 64 steps * 8192

typedef float f32x4 __attribute__((ext_vector_type(4)));
typedef unsigned short u16x8 __attribute__((ext_vector_type(8)));
typedef unsigned short u16x4 __attribute__((ext_vector_type(4)));
typedef __bf16 bf16x8 __attribute__((ext_vector_type(8)));

#define Z4 ((f32x4){0.f, 0.f, 0.f, 0.f})

// f32 -> bf16 RTNE via native cast: clang lowers to v_cvt_pk_bf16_f32 on
// gfx950 (or the RNE bit sequence) — same rounding as the hand-rolled
// version, but the compiler can pair/pack conversions (m240: compiler cast
// beats both hand bit-ops and hand asm).
static __device__ __forceinline__ unsigned short f2bf(float f) {
    __bf16 h = (__bf16)f;
    return __builtin_bit_cast(unsigned short, h);
}

// D[m][n] = sum_k A[m][k]*B[n][k] + C : A supplies m, B supplies n, frags are
// symmetric [idx16][K] -> swapping args transposes the output tile.
static __device__ __forceinline__ f32x4 mfma16(u16x8 a, u16x8 b, f32x4 c) {
    return __builtin_amdgcn_mfma_f32_16x16x32_bf16(
        __builtin_bit_cast(bf16x8, a), __builtin_bit_cast(bf16x8, b), c, 0, 0, 0);
}

// Barrier with lgkmcnt-only drain: LDS producer/consumer ordering preserved,
// but in-flight GLOBAL loads (W3, issued mid-G1, used in G3) are NOT drained
// (__syncthreads emits s_waitcnt vmcnt(0) which forces them to complete at
// B1). Safe: all inter-wave data flows through LDS; no global stores in the
// loop; same-wave global load->use ordering is handled by compiler-inserted
// counted vmcnt before first use. Correctness of this barrier was already
// validated on hardware in round 2 (passed; its regression was register
// rotation, not the barrier).
static __device__ __forceinline__ void lbar() {
    asm volatile("s_waitcnt lgkmcnt(0)" ::: "memory");
    __builtin_amdgcn_s_barrier();
    asm volatile("" ::: "memory");
}

// ---------------------------------------------------------------------------
// Kernel 1: fp32 weights -> bf16 B-fragment layout. Coalesced reads,
// scattered 16B fragment writes (L2 merges). Unchanged.
// Fragment: 64 lanes x 8 elems; slot (q*16+r) holds W[n0+r][k0+q*8 .. +7].
// ---------------------------------------------------------------------------
__global__ __launch_bounds__(256) void cvt_w_frag(
    const float* __restrict__ w1, const float* __restrict__ w2,
    const float* __restrict__ w3, unsigned short* __restrict__ ws)
{
    int gid = blockIdx.x * 256 + threadIdx.x;
    const float* src;
    unsigned short* dst;
    if (gid < 131072) {                          // W1: [s][n(64)][k(256)]
        int s = gid >> 11, rem = gid & 2047;
        int n = rem >> 5, kc = rem & 31;
        int nt = n >> 4, r = n & 15, kt = kc >> 2, q = kc & 3;
        src = w1 + (size_t)gid * 8;
        dst = ws + WS1_OFF + (size_t)s * 16384 + nt * 4096 + kt * 512 + (q * 16 + r) * 8;
    } else if (gid < 147456) {                   // W2: [s][n(32)][k(64)]
        int g = gid - 131072;
        int s = g >> 8, rem = g & 255;
        int n = rem >> 3, kc = rem & 7;
        int n2 = n >> 4, r = n & 15, kt = kc >> 2, q = kc & 3;
        src = w2 + (size_t)g * 8;
        dst = ws + WS2_OFF + (size_t)s * 2048 + n2 * 1024 + kt * 512 + (q * 16 + r) * 8;
    } else {                                     // W3: [s][n(256)][k(32)]
        int g = gid - 147456;
        int s = g >> 10, rem = g & 1023;
        int n = rem >> 2, q = rem & 3;
        int nt = n >> 4, r = n & 15;
        src = w3 + (size_t)g * 8;
        dst = ws + WS3_OFF + (size_t)s * 8192 + nt * 512 + (q * 16 + r) * 8;
    }
    float4 a = *(const float4*)src;
    float4 b = *(const float4*)(src + 4);
    u16x8 p;
    p[0] = f2bf(a.x); p[1] = f2bf(a.y); p[2] = f2bf(a.z); p[3] = f2bf(a.w);
    p[4] = f2bf(b.x); p[5] = f2bf(b.y); p[6] = f2bf(b.z); p[7] = f2bf(b.w);
    *(u16x8*)dst = p;
}

// ---------------------------------------------------------------------------
// Kernel 2: fused 8-layer x 8-expert MoE MLP, 2-expert supersteps.
// R3 structure exactly (BT=32, 4 waves, 2 blocks/CU, 2 barrier domains),
// with (a) lgkmcnt-only barriers so W3 loads stay in flight across B1/B2,
// (b) native bf16 casts in all epilogues. NO load rotation (R2 lesson:
// cross-barrier rotated state spills).
// ---------------------------------------------------------------------------
__global__ __launch_bounds__(NTHR, 2) void moe_fused(
    const float* __restrict__ src, const unsigned short* __restrict__ Wf,
    const float* __restrict__ b1, const float* __restrict__ b2,
    const float* __restrict__ b3, const float* __restrict__ masks,
    float* __restrict__ out)
{
    __shared__ __align__(16) unsigned short Xlds[BT * PX];        // 16896 B
    __shared__ __align__(16) unsigned short H1T[2][BT * PH1];     //  9216 B [row][feat]
    __shared__ __align__(16) unsigned short H2T[2][BT * PH2];     //  5120 B [row][feat]
    __shared__ float SWlds[BT * PSW];                             //  1152 B
    // total 32384 B -> 2 blocks/CU

    const int tid  = threadIdx.x;
    const int lane = tid & 63;
    const int wn   = tid >> 6;      // {0..3}: feat grp (G1), col grp (G3)
    const int rg   = wn & 1;        // G2 row group
    const int fg   = wn >> 1;       // G2 feat group
    const int n15  = lane & 15;
    const int q    = lane >> 4;
    const int b0   = blockIdx.x * BT;

    const unsigned short* w1base = Wf + WS1_OFF + wn * 4096 + lane * 8;  // feat grp wn
    const unsigned short* w2base = Wf + WS2_OFF + fg * 1024 + lane * 8;  // feat grp fg
    const unsigned short* w3base = Wf + WS3_OFF + wn * 2048 + lane * 8;  // out grp wn

    u16x8 xf[2][8];          // persistent x B-frags: rows mt*16, K=256
    f32x4 ACC[2][4];         // output accumulator (C-layout: row=q*4+rr, col=n15)

    auto stage_softmax = [&](int l) {
        if (tid < BT) {
            const float* mp = masks + ((size_t)l * BSZ + b0 + tid) * ENUM;
            float4 m0 = *(const float4*)mp;
            float4 m1 = *(const float4*)(mp + 4);
            float mv[8] = {m0.x, m0.y, m0.z, m0.w, m1.x, m1.y, m1.z, m1.w};
            float mx = mv[0];
            #pragma unroll
            for (int e = 1; e < 8; ++e) mx = fmaxf(mx, mv[e]);
            float s = 0.f;
            #pragma unroll
            for (int e = 0; e < 8; ++e) { mv[e] = expf(mv[e] - mx); s += mv[e]; }
            float inv = 1.f / s;
            #pragma unroll
            for (int e = 0; e < 8; ++e) SWlds[tid * PSW + e] = mv[e] * inv;
        }
    };

    // ACC = sum_e softmax_w[row][e] * b3[e][col]  (fp32 VALU, once per layer)
    auto acc_init = [&](int l) {
        const float* b3l = b3 + (size_t)l * ENUM * DDIM;
        #pragma unroll
        for (int mt = 0; mt < 2; ++mt)
            #pragma unroll
            for (int nt = 0; nt < 4; ++nt) ACC[mt][nt] = Z4;
        #pragma unroll 2
        for (int e2 = 0; e2 < ENUM; ++e2) {
            float swv[2][4];
            #pragma unroll
            for (int mt = 0; mt < 2; ++mt)
                #pragma unroll
                for (int rr = 0; rr < 4; ++rr)
                    swv[mt][rr] = SWlds[(mt*16 + q*4 + rr) * PSW + e2];
            #pragma unroll
            for (int nt = 0; nt < 4; ++nt) {
                float bv = b3l[e2 * DDIM + wn*64 + nt*16 + n15];
                #pragma unroll
                for (int mt = 0; mt < 2; ++mt)
                    #pragma unroll
                    for (int rr = 0; rr < 4; ++rr)
                        ACC[mt][nt][rr] += swv[mt][rr] * bv;
            }
        }
    };

    auto xf_read = [&]() {
        #pragma unroll
        for (int mt = 0; mt < 2; ++mt)
            #pragma unroll
            for (int kt = 0; kt < 8; ++kt)
                xf[mt][kt] = *(const u16x8*)
                    &Xlds[(mt*16 + n15) * PX + q*8 + kt*32];
    };
    auto x_write = [&]() {
        #pragma unroll
        for (int mt = 0; mt < 2; ++mt)
            #pragma unroll
            for (int nt = 0; nt < 4; ++nt)
                #pragma unroll
                for (int rr = 0; rr < 4; ++rr)
                    Xlds[(mt*16 + q*4 + rr) * PX + wn*64 + nt*16 + n15] =
                        f2bf(ACC[mt][nt][rr]);
    };

    // ================= prologue =================
    #pragma unroll
    for (int i = 0; i < 4; ++i) {                // stage layer-0 x (bf16)
        int o = (i * NTHR + tid) * 8;
        int r = o >> 8, c = o & 255;
        const float* p = src + (size_t)(b0 + r) * DDIM + c;
        float4 f0 = *(const float4*)(p);
        float4 f1 = *(const float4*)(p + 4);
        u16x8 pk;
        pk[0] = f2bf(f0.x); pk[1] = f2bf(f0.y); pk[2] = f2bf(f0.z); pk[3] = f2bf(f0.w);
        pk[4] = f2bf(f1.x); pk[5] = f2bf(f1.y); pk[6] = f2bf(f1.z); pk[7] = f2bf(f1.w);
        *(u16x8*)&Xlds[r * PX + c] = pk;
    }
    stage_softmax(0);
    __syncthreads();
    xf_read();
    acc_init(0);

    // ================= superstep loop: 2 experts per iteration =================
    #pragma unroll 1
    for (int ss = 0; ss < LNUM * ENUM / 2; ++ss) {
        const int s0 = 2 * ss, s1 = s0 + 1;
        const int l  = s0 >> 3, e0 = s0 & 7, e1 = s1 & 7;

        // ---- superstep-top loads: W1 both experts, W2 both, biases ----
        u16x8 wfA[8], wfB[8], w2A[2], w2B[2];
        {
            const unsigned short* pA = w1base + (size_t)s0 * 16384;
            const unsigned short* pB = w1base + (size_t)s1 * 16384;
            #pragma unroll
            for (int kt = 0; kt < 8; ++kt) {
                wfA[kt] = *(const u16x8*)(pA + kt * 512);
                wfB[kt] = *(const u16x8*)(pB + kt * 512);
            }
            const unsigned short* q2A = w2base + (size_t)s0 * 2048;
            const unsigned short* q2B = w2base + (size_t)s1 * 2048;
            w2A[0] = *(const u16x8*)(q2A);  w2A[1] = *(const u16x8*)(q2A + 512);
            w2B[0] = *(const u16x8*)(q2B);  w2B[1] = *(const u16x8*)(q2B + 512);
        }
        const float4 bb1A = *(const float4*)(b1 + s0 * 64 + wn * 16 + q * 4);
        const float4 bb1B = *(const float4*)(b1 + s1 * 64 + wn * 16 + q * 4);
        const float4 bb2A = *(const float4*)(b2 + s0 * 32 + fg * 16 + q * 4);
        const float4 bb2B = *(const float4*)(b2 + s1 * 32 + fg * 16 + q * 4);

        // ---- G1 both experts (transposed): lane -> feats wn*16+q*4+rr ----
        // 4 independent chains; B-frag xf shared by both experts.
        f32x4 a1A[2] = {Z4, Z4}, a1B[2] = {Z4, Z4};
        #pragma unroll
        for (int kt = 0; kt < 8; ++kt) {
            a1A[0] = mfma16(wfA[kt], xf[0][kt], a1A[0]);
            a1A[1] = mfma16(wfA[kt], xf[1][kt], a1A[1]);
            a1B[0] = mfma16(wfB[kt], xf[0][kt], a1B[0]);
            a1B[1] = mfma16(wfB[kt], xf[1][kt], a1B[1]);
        }

        // ---- W3 loads here (wf regs dead): used after B2; with lbar they
        //      stay in flight across B1+G2+B2 (counted vmcnt before G3) ----
        u16x8 w3A[4], w3B[4];
        {
            const unsigned short* p3A = w3base + (size_t)s0 * 8192;
            const unsigned short* p3B = w3base + (size_t)s1 * 8192;
            #pragma unroll
            for (int nt = 0; nt < 4; ++nt) {
                w3A[nt] = *(const u16x8*)(p3A + nt * 512);
                w3B[nt] = *(const u16x8*)(p3B + nt * 512);
            }
        }

        // ---- G1 epilogues: relu+bias, pack 4 feats -> one b64 per (mt,expert) ----
        #pragma unroll
        for (int mt = 0; mt < 2; ++mt) {
            u16x4 pkA, pkB;
            #pragma unroll
            for (int rr = 0; rr < 4; ++rr) {
                pkA[rr] = f2bf(fmaxf(a1A[mt][rr] + bb1A[rr], 0.f));
                pkB[rr] = f2bf(fmaxf(a1B[mt][rr] + bb1B[rr], 0.f));
            }
            int row = mt*16 + n15;
            *(u16x4*)&H1T[0][row * PH1 + wn*16 + q*4] = pkA;
            *(u16x4*)&H1T[1][row * PH1 + wn*16 + q*4] = pkB;
        }
        lbar();                             // B1: h1 ready; W3 stays in flight

        // ---- G2 both experts (transposed): lane -> h2 feats fg*16+q*4+rr,
        //      rows rg*16+n15 ----
        f32x4 a2A = Z4, a2B = Z4;
        {
            int hrow = rg*16 + n15;
            u16x8 hA0 = *(const u16x8*)&H1T[0][hrow * PH1 + q*8];
            u16x8 hA1 = *(const u16x8*)&H1T[0][hrow * PH1 + q*8 + 32];
            u16x8 hB0 = *(const u16x8*)&H1T[1][hrow * PH1 + q*8];
            u16x8 hB1 = *(const u16x8*)&H1T[1][hrow * PH1 + q*8 + 32];
            a2A = mfma16(w2A[0], hA0, a2A);
            a2B = mfma16(w2B[0], hB0, a2B);
            a2A = mfma16(w2A[1], hA1, a2A);
            a2B = mfma16(w2B[1], hB1, a2B);
        }
        {
            int row = rg*16 + n15;
            float swA = SWlds[row * PSW + e0];
            float swB = SWlds[row * PSW + e1];
            u16x4 pkA, pkB;
            #pragma unroll
            for (int rr = 0; rr < 4; ++rr) {
                pkA[rr] = f2bf(fmaxf(a2A[rr] + bb2A[rr], 0.f) * swA);
                pkB[rr] = f2bf(fmaxf(a2B[rr] + bb2B[rr], 0.f) * swB);
            }
            *(u16x4*)&H2T[0][row * PH2 + fg*16 + q*4] = pkA;
            *(u16x4*)&H2T[1][row * PH2 + fg*16 + q*4] = pkB;
        }
        lbar();                             // B2: h2 ready

        // ---- G3 both experts: ACC += h2 @ W3^T (8 independent chains) ----
        {
            u16x8 hA0 = *(const u16x8*)&H2T[0][(n15) * PH2 + q*8];
            u16x8 hA1 = *(const u16x8*)&H2T[0][(16 + n15) * PH2 + q*8];
            u16x8 hB0 = *(const u16x8*)&H2T[1][(n15) * PH2 + q*8];
            u16x8 hB1 = *(const u16x8*)&H2T[1][(16 + n15) * PH2 + q*8];
            #pragma unroll
            for (int nt = 0; nt < 4; ++nt) {
                ACC[0][nt] = mfma16(hA0, w3A[nt], ACC[0][nt]);
                ACC[1][nt] = mfma16(hA1, w3A[nt], ACC[1][nt]);
            }
            #pragma unroll
            for (int nt = 0; nt < 4; ++nt) {
                ACC[0][nt] = mfma16(hB0, w3B[nt], ACC[0][nt]);
                ACC[1][nt] = mfma16(hB1, w3B[nt], ACC[1][nt]);
            }
        }

        // ---- layer transition (e1 == 7 always lands at superstep end) ----
        if (e1 == 7 && l < LNUM - 1) {
            x_write();
            lbar();
            xf_read();
            stage_softmax(l + 1);
            lbar();
            acc_init(l + 1);
        }
    }

    // ================= final store (fp32) =================
    #pragma unroll
    for (int mt = 0; mt < 2; ++mt)
        #pragma unroll
        for (int nt = 0; nt < 4; ++nt)
            #pragma unroll
            for (int rr = 0; rr < 4; ++rr)
                out[(size_t)(b0 + mt*16 + q*4 + rr) * DDIM
                    + wn*64 + nt*16 + n15] = ACC[mt][nt][rr];
}

extern "C" void kernel_launch(void* const* d_in, const int* in_sizes, int n_in,
                              void* d_out, int out_size, void* d_ws, size_t ws_size,
                              hipStream_t stream) {
    const float* src   = (const float*)d_in[0];
    const float* W1    = (const float*)d_in[1];
    const float* b1    = (const float*)d_in[2];
    const float* W2    = (const float*)d_in[3];
    const float* b2    = (const float*)d_in[4];
    const float* W3    = (const float*)d_in[5];
    const float* b3    = (const float*)d_in[6];
    const float* masks = (const float*)d_in[7];
    float* out = (float*)d_out;
    unsigned short* ws = (unsigned short*)d_ws;   // needs 3,407,872 B

    hipLaunchKernelGGL(cvt_w_frag, dim3(832), dim3(256), 0, stream, W1, W2, W3, ws);
    hipLaunchKernelGGL(moe_fused, dim3(BSZ / BT), dim3(NTHR), 0, stream,
                       src, ws, b1, b2, b3, masks, out);
}